// Round 1
// baseline (72.835 us; speedup 1.0000x reference)
//
#include <hip/hip_runtime.h>

// PatchChamferDistance: B=32, G=64, P=256, D=3 -> BG=2048 patches.
// dist2[i][j] = ||p_i||^2 + ||t_j||^2 - 2 p_i.t_j (clamped >= 0)
// out = mean over patches of (mean_i min_j + mean_j min_i)
//
// Round 8: 32x32x16 dual-orientation MFMA. History: r1/r3/r5 ~84 us with a
// ~13 us VALU kernel; r7 (16x16x32 MFMA) hit 81.1 us (~10 us kernel) but kept
// a 256-op ds_swizzle rowmin butterfly (64 dependent 4-deep shuffle chains
// per patch) -> latency-bound. This round:
//  - mfma_f32_32x32x16_f16: 1024 pairs per MFMA at ~8cy. Matrix pipe has so
//    much slack we compute each pair TWICE (D rows=pred, Dt rows=tgt via
//    operand swap) and total MFMA cycles still DROP vs r7.
//  - both chamfer directions now reduce over the 16 accumulator regs
//    (7 v_min3 + 1 v_min per tile, lane-local). Cross-lane traffic is just
//    one __shfl_xor(32) per 32-point block: 16/patch vs r7's ~290.
//  - both norms ride in the dot product as f16 hi/lo pairs with '1' slots on
//    the other operand (K usage 7 of 8), C = 0 inline -> no per-tile LDS C-init.
//  - robustness: A/B share the (half,slot)->k map (any consistent HW k
//    permutation cancels); C/D layout col=lane&31, row=(reg&3)+8*(reg>>2)
//    +4*(lane>>5) (m74/m101-verified) used only via "lanes l, l^32 partition
//    the 32 rows" -> min+sum invariant to permutations.
// Precision: coords f16 RTNE (symmetric, as r7: dist2 err ~2e-3 vs threshold
// 7.93e-3); norms f16 hi+lo split, abs err ~1.5e-5. Products f16*f16 are
// exact in fp32 accumulation.

#define NPATCH 2048
#define NPTS   256

typedef _Float16 f16x8  __attribute__((ext_vector_type(8)));
typedef float    f32x16 __attribute__((ext_vector_type(16)));

__device__ __forceinline__ float min16(f32x16 d) {
    // 16 -> 1 min tree shaped for v_min3_f32 fusion (7 min3 + 1 min).
    float a = fminf(fminf(d[0],  d[1]),  d[2]);
    float b = fminf(fminf(d[3],  d[4]),  d[5]);
    float c = fminf(fminf(d[6],  d[7]),  d[8]);
    float e = fminf(fminf(d[9],  d[10]), d[11]);
    float f = fminf(fminf(d[12], d[13]), d[14]);
    float g = fminf(fminf(a, b), c);
    float h = fminf(fminf(e, f), d[15]);
    return fminf(g, h);
}

__global__ __launch_bounds__(256, 2) void chamfer_mfma_kernel(
    const float* __restrict__ pred,
    const float* __restrict__ tgt,
    float* __restrict__ partial)
{
    __shared__ __align__(16) float sP[4][4][NPTS];  // 4 patches x {x,y,z,norm}
    __shared__ __align__(16) float sT[4][4][NPTS];

    const int tid = threadIdx.x;

    // Stage 4 patches' SoA planes (whole block cooperates); norms in fp32
    // from the ORIGINAL coords (r7-proven).
    {
        const size_t pbase = (size_t)blockIdx.x * 4 * (NPTS * 3);
#pragma unroll
        for (int pp = 0; pp < 4; ++pp) {
            const float* __restrict__ pb = pred + pbase + pp * (NPTS * 3);
            const float* __restrict__ tb = tgt  + pbase + pp * (NPTS * 3);
            float x = pb[3 * tid + 0], y = pb[3 * tid + 1], z = pb[3 * tid + 2];
            sP[pp][0][tid] = x; sP[pp][1][tid] = y; sP[pp][2][tid] = z;
            sP[pp][3][tid] = fmaf(z, z, fmaf(y, y, x * x));
            x = tb[3 * tid + 0]; y = tb[3 * tid + 1]; z = tb[3 * tid + 2];
            sT[pp][0][tid] = x; sT[pp][1][tid] = y; sT[pp][2][tid] = z;
            sT[pp][3][tid] = fmaf(z, z, fmaf(y, y, x * x));
        }
    }
    __syncthreads();

    const int wave = tid >> 6;      // one wave = one patch
    const int lane = tid & 63;
    const int c    = lane & 31;     // row/col index within 32-block
    const bool h0  = (lane >> 5) == 0;  // half0 carries k=0..7
    const int pp   = wave;

    const f16x8  zf = {};           // zero input frag (other half: k>=8 all 0)
    const f32x16 zc = {};           // C = 0 (both norms ride in the dot)

    const _Float16 one = (_Float16)1.0f;
    const _Float16 m2  = (_Float16)(-2.0f);
    const _Float16 z16 = (_Float16)0.0f;

    // Build all 8 target blocks' frags once per patch:
    //   Bt (B-operand, cols=tgt):  { x, y, z, 1, 1, nh, nl, 0}
    //   At (A-operand, rows=tgt):  {-2x,-2y,-2z, nh, nl, 1, 1, 0}
    f16x8 At[8], Bt[8];
    float bacc[8];
#pragma unroll
    for (int tb = 0; tb < 8; ++tb) {
        const int idx = tb * 32 + c;
        const float x = sT[pp][0][idx], y = sT[pp][1][idx], z = sT[pp][2][idx];
        const float n = sT[pp][3][idx];
        const _Float16 xh = (_Float16)x, yh = (_Float16)y, zh = (_Float16)z;
        const _Float16 nh = (_Float16)n;
        const _Float16 nl = (_Float16)(n - (float)nh);   // residual, exact-ish
        f16x8 bv = {xh, yh, zh, one, one, nh, nl, z16};
        f16x8 av = {m2 * xh, m2 * yh, m2 * zh, nh, nl, one, one, z16};
        Bt[tb] = h0 ? bv : zf;
        At[tb] = h0 ? av : zf;
        bacc[tb] = 1e30f;
    }

    float sf = 0.0f, sb = 0.0f;

#pragma unroll 1
    for (int ib = 0; ib < 8; ++ib) {
        // Pred block frags:
        //   Ap (A-operand, rows=pred): {-2x,-2y,-2z, nh, nl, 1, 1, 0}
        //   Bp (B-operand, cols=pred): { x, y, z, 1, 1, nh, nl, 0}
        const int idx = ib * 32 + c;
        const float x = sP[pp][0][idx], y = sP[pp][1][idx], z = sP[pp][2][idx];
        const float n = sP[pp][3][idx];
        const _Float16 xh = (_Float16)x, yh = (_Float16)y, zh = (_Float16)z;
        const _Float16 nh = (_Float16)n;
        const _Float16 nl = (_Float16)(n - (float)nh);
        f16x8 apv = {m2 * xh, m2 * yh, m2 * zh, nh, nl, one, one, z16};
        f16x8 bpv = {xh, yh, zh, one, one, nh, nl, z16};
        const f16x8 Ap = h0 ? apv : zf;
        const f16x8 Bp = h0 ? bpv : zf;

        float fmin_ = 1e30f;
#pragma unroll
        for (int tb = 0; tb < 8; ++tb) {
            // D : rows = pred(ib), cols = tgt(tb)  -> backward (min over preds)
            // Dt: rows = tgt(tb),  cols = pred(ib) -> forward  (min over tgts)
            f32x16 D  = __builtin_amdgcn_mfma_f32_32x32x16_f16(Ap, Bt[tb], zc, 0, 0, 0);
            f32x16 Dt = __builtin_amdgcn_mfma_f32_32x32x16_f16(At[tb], Bp, zc, 0, 0, 0);
            bacc[tb] = fminf(bacc[tb], min16(D));   // lane-local over 16 rows
            fmin_    = fminf(fmin_,    min16(Dt));
        }
        // Combine the two half-wave row partitions; pred point = ib*32 + c,
        // duplicated across the lane pair -> weight 1/2 at the end.
        fmin_ = fminf(fmin_, __shfl_xor(fmin_, 32, 64));
        sf += fmaxf(fmin_, 0.0f);   // clamp commutes with min (monotone)
    }

    // Backward: same half-combine per target block.
#pragma unroll
    for (int tb = 0; tb < 8; ++tb) {
        float v = fminf(bacc[tb], __shfl_xor(bacc[tb], 32, 64));
        sb += fmaxf(v, 0.0f);
    }

    // Each point counted twice (two halves) -> x0.5.
    float tot = (sf + sb) * 0.5f;
#pragma unroll
    for (int off = 32; off > 0; off >>= 1)
        tot += __shfl_down(tot, off, 64);
    if (lane == 0) partial[blockIdx.x * 4 + wave] = tot;
}

__global__ __launch_bounds__(256) void chamfer_reduce_kernel(
    const float* __restrict__ partial,
    float* __restrict__ out)
{
    __shared__ float red[4];
    const int tid = threadIdx.x;
    float s = 0.0f;
#pragma unroll
    for (int i = tid; i < NPATCH; i += 256) s += partial[i];
#pragma unroll
    for (int off = 32; off > 0; off >>= 1)
        s += __shfl_down(s, off, 64);
    if ((tid & 63) == 0) red[tid >> 6] = s;
    __syncthreads();
    if (tid == 0)
        out[0] = (red[0] + red[1] + red[2] + red[3]) *
                 (1.0f / ((float)NPTS * (float)NPATCH));
}

extern "C" void kernel_launch(void* const* d_in, const int* in_sizes, int n_in,
                              void* d_out, int out_size, void* d_ws, size_t ws_size,
                              hipStream_t stream) {
    const float* pred = (const float*)d_in[0];
    const float* tgt  = (const float*)d_in[1];
    float* partial    = (float*)d_ws;      // 2048 floats = 8 KB scratch
    float* out        = (float*)d_out;

    chamfer_mfma_kernel<<<NPATCH / 4, 256, 0, stream>>>(pred, tgt, partial);
    chamfer_reduce_kernel<<<1, 256, 0, stream>>>(partial, out);
}

// Round 2
// 72.662 us; speedup vs baseline: 1.0024x; 1.0024x over previous
//
#include <hip/hip_runtime.h>

// PatchChamferDistance: B=32, G=64, P=256, D=3 -> BG=2048 patches.
// dist2[i][j] = ||p_i||^2 + ||t_j||^2 - 2 p_i.t_j (clamped >= 0)
// out = mean over patches of (mean_i min_j + mean_j min_i)
//
// Round 9: overhead polish. r8 (dual-orientation 32x32x16 MFMA) hit 72.835 us
// with absmax 0.0; per session history (r1/r3/r5 = 84.0 @ ~13 us kernel,
// r7 = 81.1 @ ~10 us) the fixed harness floor is ~69-70 us -> main+reduce are
// now only ~3-4 us combined. Profile top-5 is 100% harness 256 MiB workspace
// poison fills (40.9 us @ 82% HBM peak) - untouchable. Remaining controllables:
//  - reduce dispatch reads 2048 floats (8 strided loads/thread, latency tail):
//    main kernel now combines its 4 wave-totals in LDS -> partial[512],
//    reduce does 2 loads/thread.
//  - ib loop '#pragma unroll 1' blocked cross-iteration ILP (frag-build VALU
//    vs previous iteration's MFMA + min tree): unroll 2, VGPR ~200 < 256
//    budget of launch_bounds(256,2).
// DO NOT re-fuse the two kernels: r4 (fence storm) and r6 (atomic+small grid)
// both regressed - dispatch overhead is cheaper than grid-sync/atomic tails.
// Precision scheme unchanged (r7/r8-proven): coords f16 RTNE symmetric
// (dist2 err ~2e-3 vs threshold 7.93e-3), norms ride in the dot as f16 hi/lo
// pairs (err ~1.5e-5), C = 0 inline.

#define NPATCH 2048
#define NPTS   256

typedef _Float16 f16x8  __attribute__((ext_vector_type(8)));
typedef float    f32x16 __attribute__((ext_vector_type(16)));

__device__ __forceinline__ float min16(f32x16 d) {
    // 16 -> 1 min tree shaped for v_min3_f32 fusion (7 min3 + 1 min).
    float a = fminf(fminf(d[0],  d[1]),  d[2]);
    float b = fminf(fminf(d[3],  d[4]),  d[5]);
    float c = fminf(fminf(d[6],  d[7]),  d[8]);
    float e = fminf(fminf(d[9],  d[10]), d[11]);
    float f = fminf(fminf(d[12], d[13]), d[14]);
    float g = fminf(fminf(a, b), c);
    float h = fminf(fminf(e, f), d[15]);
    return fminf(g, h);
}

__global__ __launch_bounds__(256, 2) void chamfer_mfma_kernel(
    const float* __restrict__ pred,
    const float* __restrict__ tgt,
    float* __restrict__ partial)
{
    __shared__ __align__(16) float sP[4][4][NPTS];  // 4 patches x {x,y,z,norm}
    __shared__ __align__(16) float sT[4][4][NPTS];
    __shared__ float wsum[4];

    const int tid = threadIdx.x;

    // Stage 4 patches' SoA planes (whole block cooperates); norms in fp32
    // from the ORIGINAL coords (r7-proven).
    {
        const size_t pbase = (size_t)blockIdx.x * 4 * (NPTS * 3);
#pragma unroll
        for (int pp = 0; pp < 4; ++pp) {
            const float* __restrict__ pb = pred + pbase + pp * (NPTS * 3);
            const float* __restrict__ tb = tgt  + pbase + pp * (NPTS * 3);
            float x = pb[3 * tid + 0], y = pb[3 * tid + 1], z = pb[3 * tid + 2];
            sP[pp][0][tid] = x; sP[pp][1][tid] = y; sP[pp][2][tid] = z;
            sP[pp][3][tid] = fmaf(z, z, fmaf(y, y, x * x));
            x = tb[3 * tid + 0]; y = tb[3 * tid + 1]; z = tb[3 * tid + 2];
            sT[pp][0][tid] = x; sT[pp][1][tid] = y; sT[pp][2][tid] = z;
            sT[pp][3][tid] = fmaf(z, z, fmaf(y, y, x * x));
        }
    }
    __syncthreads();

    const int wave = tid >> 6;      // one wave = one patch
    const int lane = tid & 63;
    const int c    = lane & 31;     // row/col index within 32-block
    const bool h0  = (lane >> 5) == 0;  // half0 carries k=0..7
    const int pp   = wave;

    const f16x8  zf = {};           // zero input frag (other half: k>=8 all 0)
    const f32x16 zc = {};           // C = 0 (both norms ride in the dot)

    const _Float16 one = (_Float16)1.0f;
    const _Float16 m2  = (_Float16)(-2.0f);
    const _Float16 z16 = (_Float16)0.0f;

    // Build all 8 target blocks' frags once per patch:
    //   Bt (B-operand, cols=tgt):  { x, y, z, 1, 1, nh, nl, 0}
    //   At (A-operand, rows=tgt):  {-2x,-2y,-2z, nh, nl, 1, 1, 0}
    f16x8 At[8], Bt[8];
    float bacc[8];
#pragma unroll
    for (int tb = 0; tb < 8; ++tb) {
        const int idx = tb * 32 + c;
        const float x = sT[pp][0][idx], y = sT[pp][1][idx], z = sT[pp][2][idx];
        const float n = sT[pp][3][idx];
        const _Float16 xh = (_Float16)x, yh = (_Float16)y, zh = (_Float16)z;
        const _Float16 nh = (_Float16)n;
        const _Float16 nl = (_Float16)(n - (float)nh);   // residual, exact-ish
        f16x8 bv = {xh, yh, zh, one, one, nh, nl, z16};
        f16x8 av = {m2 * xh, m2 * yh, m2 * zh, nh, nl, one, one, z16};
        Bt[tb] = h0 ? bv : zf;
        At[tb] = h0 ? av : zf;
        bacc[tb] = 1e30f;
    }

    float sf = 0.0f, sb = 0.0f;

#pragma unroll 2
    for (int ib = 0; ib < 8; ++ib) {
        // Pred block frags:
        //   Ap (A-operand, rows=pred): {-2x,-2y,-2z, nh, nl, 1, 1, 0}
        //   Bp (B-operand, cols=pred): { x, y, z, 1, 1, nh, nl, 0}
        const int idx = ib * 32 + c;
        const float x = sP[pp][0][idx], y = sP[pp][1][idx], z = sP[pp][2][idx];
        const float n = sP[pp][3][idx];
        const _Float16 xh = (_Float16)x, yh = (_Float16)y, zh = (_Float16)z;
        const _Float16 nh = (_Float16)n;
        const _Float16 nl = (_Float16)(n - (float)nh);
        f16x8 apv = {m2 * xh, m2 * yh, m2 * zh, nh, nl, one, one, z16};
        f16x8 bpv = {xh, yh, zh, one, one, nh, nl, z16};
        const f16x8 Ap = h0 ? apv : zf;
        const f16x8 Bp = h0 ? bpv : zf;

        float fmin_ = 1e30f;
#pragma unroll
        for (int tb = 0; tb < 8; ++tb) {
            // D : rows = pred(ib), cols = tgt(tb)  -> backward (min over preds)
            // Dt: rows = tgt(tb),  cols = pred(ib) -> forward  (min over tgts)
            f32x16 D  = __builtin_amdgcn_mfma_f32_32x32x16_f16(Ap, Bt[tb], zc, 0, 0, 0);
            f32x16 Dt = __builtin_amdgcn_mfma_f32_32x32x16_f16(At[tb], Bp, zc, 0, 0, 0);
            bacc[tb] = fminf(bacc[tb], min16(D));   // lane-local over 16 rows
            fmin_    = fminf(fmin_,    min16(Dt));
        }
        // Combine the two half-wave row partitions; pred point = ib*32 + c,
        // duplicated across the lane pair -> weight 1/2 at the end.
        fmin_ = fminf(fmin_, __shfl_xor(fmin_, 32, 64));
        sf += fmaxf(fmin_, 0.0f);   // clamp commutes with min (monotone)
    }

    // Backward: same half-combine per target block.
#pragma unroll
    for (int tb = 0; tb < 8; ++tb) {
        float v = fminf(bacc[tb], __shfl_xor(bacc[tb], 32, 64));
        sb += fmaxf(v, 0.0f);
    }

    // Each point counted twice (two halves) -> x0.5.
    float tot = (sf + sb) * 0.5f;
#pragma unroll
    for (int off = 32; off > 0; off >>= 1)
        tot += __shfl_down(tot, off, 64);

    // Combine the 4 wave totals -> one partial per block (512 total): cuts
    // the reduce kernel's loads 4x.
    if (lane == 0) wsum[wave] = tot;
    __syncthreads();
    if (tid == 0)
        partial[blockIdx.x] = (wsum[0] + wsum[1]) + (wsum[2] + wsum[3]);
}

__global__ __launch_bounds__(256) void chamfer_reduce_kernel(
    const float* __restrict__ partial,
    float* __restrict__ out)
{
    __shared__ float red[4];
    const int tid = threadIdx.x;
    float s = partial[tid] + partial[tid + 256];   // 512 block-partials
#pragma unroll
    for (int off = 32; off > 0; off >>= 1)
        s += __shfl_down(s, off, 64);
    if ((tid & 63) == 0) red[tid >> 6] = s;
    __syncthreads();
    if (tid == 0)
        out[0] = (red[0] + red[1] + red[2] + red[3]) *
                 (1.0f / ((float)NPTS * (float)NPATCH));
}

extern "C" void kernel_launch(void* const* d_in, const int* in_sizes, int n_in,
                              void* d_out, int out_size, void* d_ws, size_t ws_size,
                              hipStream_t stream) {
    const float* pred = (const float*)d_in[0];
    const float* tgt  = (const float*)d_in[1];
    float* partial    = (float*)d_ws;      // 512 floats = 2 KB scratch
    float* out        = (float*)d_out;

    chamfer_mfma_kernel<<<NPATCH / 4, 256, 0, stream>>>(pred, tgt, partial);
    chamfer_reduce_kernel<<<1, 256, 0, stream>>>(partial, out);
}